// Round 3
// baseline (108.807 us; speedup 1.0000x reference)
//
#include <hip/hip_runtime.h>
#include <float.h>

#define W  128
#define NB 50

typedef float f32x4 __attribute__((ext_vector_type(4)));

__global__ __launch_bounds__(256) void mtf_kernel(const float* __restrict__ X,
                                                  float* __restrict__ out) {
    __shared__ int   bins[W];
    __shared__ int   hist[NB * NB];
    __shared__ int   rowsum[NB];
    __shared__ float rinv[NB];
    __shared__ __align__(16) float G[NB * W];   // G[rb][c] = P[rb][bins[c]]
    __shared__ float redmin[4], redmax[4];

    const int tid = threadIdx.x;
    const int s   = blockIdx.x;
    const float* xrow = X + (size_t)s * W;

    // ---- Phase 1: load + min/max reduction (wave = 64 lanes) ----
    float v = 0.0f;
    float vmin = FLT_MAX, vmax = -FLT_MAX;
    if (tid < W) { v = xrow[tid]; vmin = v; vmax = v; }
    #pragma unroll
    for (int off = 32; off >= 1; off >>= 1) {
        vmin = fminf(vmin, __shfl_down(vmin, off, 64));
        vmax = fmaxf(vmax, __shfl_down(vmax, off, 64));
    }
    if ((tid & 63) == 0) { redmin[tid >> 6] = vmin; redmax[tid >> 6] = vmax; }

    // zero histogram + rowsums while the reduction lands
    for (int i = tid; i < NB * NB; i += 256) hist[i] = 0;
    if (tid < NB) rowsum[tid] = 0;
    __syncthreads();

    const float mn = fminf(fminf(redmin[0], redmin[1]), fminf(redmin[2], redmin[3]));
    const float mx = fmaxf(fmaxf(redmax[0], redmax[1]), fmaxf(redmax[2], redmax[3]));
    const float d  = (mx - mn) + 1e-6f;   // matches (X_max - X_min + EPS) in fp32

    // ---- Phase 2: bucketize (searchsorted side='left': #{edge < x}) ----
    if (tid < W) {
        float q   = (v - mn) / d;
        float xsc = q * 2.0f - 1.0f;      // *2 exact; fma contraction harmless
        double xd = (double)xsc;
        int b = 0;
        #pragma unroll
        for (int k = 1; k <= NB - 1; ++k) {
            double bk = -1.0 + 0.04 * (double)k;   // linspace inner edges (fp64)
            b += (bk < xd) ? 1 : 0;
        }
        bins[tid] = b;
    }
    __syncthreads();

    // ---- Phase 3: transition histogram + row sums (LDS atomics, 127 incs) ----
    if (tid < W - 1) {
        int bi = bins[tid], bj = bins[tid + 1];
        atomicAdd(&hist[bi * NB + bj], 1);
        atomicAdd(&rowsum[bi], 1);
    }
    __syncthreads();

    // ---- Phase 4: per-row reciprocal (50 divs; rcp-mul err ~1e-7 << 2e-2 thr) ----
    if (tid < NB) {
        int rs = rowsum[tid];
        rinv[tid] = 1.0f / (float)(rs == 0 ? 1 : rs);
    }
    __syncthreads();

    // ---- Phase 5a: build gathered-column table G[rb][c] = hist[rb][bins[c]] * rinv[rb]
    // 6400 elems; bins[c] read is contiguous (free), hist read is the only random-bank op.
    for (int i = tid; i < NB * W; i += 256) {
        int rb = i >> 7;          // i / W
        int c  = i & (W - 1);     // i % W
        G[i] = (float)hist[rb * NB + bins[c]] * rinv[rb];
    }
    __syncthreads();

    // ---- Phase 5b: emit — contiguous ds_read_b128 from G + coalesced nt stores ----
    float* orow = out + (size_t)s * W * W;
    const int c4 = (tid & 31) * 4;        // half-wave covers one 512B row
    const int r0 = tid >> 5;
    #pragma unroll
    for (int it = 0; it < 16; ++it) {
        int row = r0 + it * 8;
        int rb  = bins[row];              // LDS broadcast across the half-wave
        f32x4 o = *(const f32x4*)&G[rb * W + c4];
        __builtin_nontemporal_store(o, (f32x4*)(orow + row * W + c4));
    }
}

extern "C" void kernel_launch(void* const* d_in, const int* in_sizes, int n_in,
                              void* d_out, int out_size, void* d_ws, size_t ws_size,
                              hipStream_t stream) {
    const float* X = (const float*)d_in[0];
    float* out = (float*)d_out;
    int S = in_sizes[0] / W;               // 256*6 = 1536 series
    mtf_kernel<<<dim3(S), dim3(256), 0, stream>>>(X, out);
}

// Round 4
// 105.923 us; speedup vs baseline: 1.0272x; 1.0272x over previous
//
#include <hip/hip_runtime.h>
#include <float.h>

#define W  128
#define NB 50

typedef float f32x4 __attribute__((ext_vector_type(4)));

// __launch_bounds__(256,4): 4 waves/SIMD => 128 VGPR cap, enough for the
// 8x f32x4 staging array; matches the 4-blocks/CU LDS limit (36.5 KB/block).
__global__ __launch_bounds__(256, 4) void mtf_kernel(const float* __restrict__ X,
                                                     float* __restrict__ out) {
    __shared__ int   bins[W];
    __shared__ int   hist[NB * NB];
    __shared__ int   rowsum[NB];
    __shared__ float rinv[NB];
    __shared__ __align__(16) float G[NB * W];   // G[rb][c] = P[rb][bins[c]]
    __shared__ float redmin[4], redmax[4];

    const int tid = threadIdx.x;
    const int s   = blockIdx.x;
    const float* xrow = X + (size_t)s * W;

    // ---- Phase 1: load + min/max reduction (wave = 64 lanes) ----
    float v = 0.0f;
    float vmin = FLT_MAX, vmax = -FLT_MAX;
    if (tid < W) { v = xrow[tid]; vmin = v; vmax = v; }
    #pragma unroll
    for (int off = 32; off >= 1; off >>= 1) {
        vmin = fminf(vmin, __shfl_down(vmin, off, 64));
        vmax = fmaxf(vmax, __shfl_down(vmax, off, 64));
    }
    if ((tid & 63) == 0) { redmin[tid >> 6] = vmin; redmax[tid >> 6] = vmax; }

    // zero histogram + rowsums while the reduction lands
    for (int i = tid; i < NB * NB; i += 256) hist[i] = 0;
    if (tid < NB) rowsum[tid] = 0;
    __syncthreads();

    const float mn = fminf(fminf(redmin[0], redmin[1]), fminf(redmin[2], redmin[3]));
    const float mx = fmaxf(fmaxf(redmax[0], redmax[1]), fmaxf(redmax[2], redmax[3]));
    const float d  = (mx - mn) + 1e-6f;   // matches (X_max - X_min + EPS) in fp32

    // ---- Phase 2: bucketize (searchsorted side='left': #{edge < x}) ----
    if (tid < W) {
        float q   = (v - mn) / d;
        float xsc = q * 2.0f - 1.0f;      // *2 exact; fma contraction harmless
        double xd = (double)xsc;
        int b = 0;
        #pragma unroll
        for (int k = 1; k <= NB - 1; ++k) {
            double bk = -1.0 + 0.04 * (double)k;   // linspace inner edges (fp64)
            b += (bk < xd) ? 1 : 0;
        }
        bins[tid] = b;
    }
    __syncthreads();

    // ---- Phase 3: transition histogram + row sums (LDS atomics, 127 incs) ----
    if (tid < W - 1) {
        int bi = bins[tid], bj = bins[tid + 1];
        atomicAdd(&hist[bi * NB + bj], 1);
        atomicAdd(&rowsum[bi], 1);
    }
    __syncthreads();

    // ---- Phase 4: per-row reciprocal (50 divs; rcp-mul err ~1e-7 << 2e-2 thr) ----
    if (tid < NB) {
        int rs = rowsum[tid];
        rinv[tid] = 1.0f / (float)(rs == 0 ? 1 : rs);
    }
    __syncthreads();

    // ---- Phase 5a: G[rb][c] = hist[rb][bins[c]] * rinv[rb]
    // stride 256 == 0 mod 128 => column c is loop-invariant per thread:
    // ONE bins read, then 25 independent (pipelineable) hist reads.
    {
        const int c   = tid & (W - 1);
        const int bc  = bins[c];
        const int rb0 = tid >> 7;          // 0 or 1; wave-uniform
        #pragma unroll
        for (int k = 0; k < NB / 2; ++k) {
            int rb = rb0 + 2 * k;
            G[rb * W + c] = (float)hist[rb * NB + bc] * rinv[rb];
        }
    }
    __syncthreads();

    // ---- Phase 5b: stage-then-store, 2 batches of 8 ----
    // Batch = 8 ds_read_b128 into regs, then 8 back-to-back dwordx4 stores:
    // keeps the store stream continuous instead of per-iter lgkm/vm round-trips.
    float* orow = out + (size_t)s * W * W;
    const int c4 = (tid & 31) * 4;        // half-wave covers one 512B row
    const int r0 = tid >> 5;
    #pragma unroll
    for (int half = 0; half < 2; ++half) {
        f32x4 vals[8];
        #pragma unroll
        for (int it = 0; it < 8; ++it) {
            int row = r0 + (half * 8 + it) * 8;
            vals[it] = *(const f32x4*)&G[bins[row] * W + c4];
        }
        #pragma unroll
        for (int it = 0; it < 8; ++it) {
            int row = r0 + (half * 8 + it) * 8;
            *(f32x4*)(orow + row * W + c4) = vals[it];
        }
    }
}

extern "C" void kernel_launch(void* const* d_in, const int* in_sizes, int n_in,
                              void* d_out, int out_size, void* d_ws, size_t ws_size,
                              hipStream_t stream) {
    const float* X = (const float*)d_in[0];
    float* out = (float*)d_out;
    int S = in_sizes[0] / W;               // 256*6 = 1536 series
    mtf_kernel<<<dim3(S), dim3(256), 0, stream>>>(X, out);
}